// Round 10
// baseline (4273.140 us; speedup 1.0000x reference)
//
#include <hip/hip_runtime.h>
#include <hip/hip_fp16.h>

// Problem constants
#define NB   64     // batch
#define NDEC 12     // decoder steps
#define NF   32     // input features
#define NH   512    // hidden
#define NE   96     // encoder length
#define NT   4      // output dim
#define NBLK 256    // persistent grid (1 block/CU guaranteed -> coop launch legal)

__device__ __forceinline__ float fast_tanh(float x) {
    x = fminf(fmaxf(x, -15.f), 15.f);
    float e = __expf(2.f * x);
    return (e - 1.f) / (e + 1.f);
}
__device__ __forceinline__ float fast_sig(float x) {
    return 1.f / (1.f + __expf(-x));
}

// ---------------------------------------------------------------------------
// One-time fused fp32 -> fp16 conversions (+ Wa_h transpose) + barrier-ctr zero
__global__ __launch_bounds__(256) void k_prep(
    const float* __restrict__ Wi0, const float* __restrict__ Wh0,
    const float* __restrict__ Wi1, const float* __restrict__ Wh1,
    const float* __restrict__ Wout, const float* __restrict__ Wattn,
    __half* __restrict__ Wi0h, __half* __restrict__ Wh0h,
    __half* __restrict__ Wi1h, __half* __restrict__ Wh1h,
    __half* __restrict__ Wouth, __half* __restrict__ WahT,
    unsigned int* __restrict__ ctr)
{
    int i = blockIdx.x*256 + threadIdx.x;
    const int n0 = 1536*544, n1 = 1536*512, n4 = 4*1056, n5 = 512*512;
    if (i < n0) { Wi0h[i] = __float2half_rn(Wi0[i]); return; }  i -= n0;
    if (i < n1) { Wh0h[i] = __float2half_rn(Wh0[i]); return; }  i -= n1;
    if (i < n1) { Wi1h[i] = __float2half_rn(Wi1[i]); return; }  i -= n1;
    if (i < n1) { Wh1h[i] = __float2half_rn(Wh1[i]); return; }  i -= n1;
    if (i < n4) { Wouth[i] = __float2half_rn(Wout[i]); return; } i -= n4;
    if (i < n5) {
        int k = i >> 9, g = i & 511;                 // WahT[k][g] = Wattn[g][k]
        WahT[i] = __float2half_rn(Wattn[(size_t)g*1024 + k]);
        return;
    }
    i -= n5;
    if (i < 64) ctr[i] = 0u;
}

// ---------------------------------------------------------------------------
// Init: h0/h1 col-major [512][64], h1 row copy [64][512], cur(0) col [32][64]
__global__ __launch_bounds__(256) void k_init(const float* __restrict__ hidden,
                                              const float* __restrict__ inputs,
                                              float* __restrict__ h0c, float* __restrict__ h1c,
                                              float* __restrict__ h1row,
                                              float* __restrict__ curc) {
    int b = blockIdx.x, t = threadIdx.x;
    for (int k = t; k < NH; k += 256) {
        float v0 = hidden[b*NH + k];
        float v1 = hidden[NB*NH + b*NH + k];
        h0c[k*NB + b] = v0;
        h1c[k*NB + b] = v1;
        h1row[b*NH + k] = v1;
    }
    if (t < NF) curc[t*NB + b] = inputs[b*NDEC*NF + t];
}

// ---------------------------------------------------------------------------
// enc_proj[be][g] = sum_h enc[be][h] * W_attn[g][512+h]; stored fp16
__global__ __launch_bounds__(256) void k_encproj(const float* __restrict__ enc,
                                                 const float* __restrict__ Wattn,
                                                 __half* __restrict__ encph) {
    __shared__ float As[64][17];
    __shared__ float Bs[64][17];
    int bx = blockIdx.x & 7;    // g tile
    int by = blockIdx.x >> 3;   // be tile
    int tid = threadIdx.x;
    int tx = tid & 15, ty = tid >> 4;
    int arow = tid >> 2;
    int akk  = (tid & 3) * 4;
    const float* Abase = enc   + (size_t)(by*64 + arow)*NH;
    const float* Bbase = Wattn + (size_t)(bx*64 + arow)*(2*NH) + NH;
    float acc[4][4] = {};
    for (int k0 = 0; k0 < NH; k0 += 16) {
        float4 av = *(const float4*)(Abase + k0 + akk);
        float4 bv = *(const float4*)(Bbase + k0 + akk);
        As[arow][akk+0] = av.x; As[arow][akk+1] = av.y;
        As[arow][akk+2] = av.z; As[arow][akk+3] = av.w;
        Bs[arow][akk+0] = bv.x; Bs[arow][akk+1] = bv.y;
        Bs[arow][akk+2] = bv.z; Bs[arow][akk+3] = bv.w;
        __syncthreads();
        #pragma unroll 4
        for (int k = 0; k < 16; ++k) {
            float a0 = As[ty*4+0][k], a1 = As[ty*4+1][k], a2 = As[ty*4+2][k], a3 = As[ty*4+3][k];
            float b0 = Bs[tx*4+0][k], b1 = Bs[tx*4+1][k], b2 = Bs[tx*4+2][k], b3 = Bs[tx*4+3][k];
            acc[0][0] += a0*b0; acc[0][1] += a0*b1; acc[0][2] += a0*b2; acc[0][3] += a0*b3;
            acc[1][0] += a1*b0; acc[1][1] += a1*b1; acc[1][2] += a1*b2; acc[1][3] += a1*b3;
            acc[2][0] += a2*b0; acc[2][1] += a2*b1; acc[2][2] += a2*b2; acc[2][3] += a2*b3;
            acc[3][0] += a3*b0; acc[3][1] += a3*b1; acc[3][2] += a3*b2; acc[3][3] += a3*b3;
        }
        __syncthreads();
    }
    #pragma unroll
    for (int i = 0; i < 4; ++i)
        #pragma unroll
        for (int j = 0; j < 4; ++j)
            encph[(size_t)(by*64 + ty*4 + i)*NH + bx*64 + tx*4 + j] = __float2half_rn(acc[i][j]);
}

// ---------------------------------------------------------------------------
// Flag-based device barrier: release fence -> count -> spin -> acquire fence.
// LDS contents survive the cache invalidation (weights stay pinned).
__device__ __forceinline__ void gbar(unsigned int* ctr) {
    __syncthreads();
    if (threadIdx.x == 0) {
        __threadfence();   // release prior global writes
        __hip_atomic_fetch_add(ctr, 1u, __ATOMIC_RELEASE, __HIP_MEMORY_SCOPE_AGENT);
        while (__hip_atomic_load(ctr, __ATOMIC_ACQUIRE, __HIP_MEMORY_SCOPE_AGENT) < NBLK)
            __builtin_amdgcn_s_sleep(8);
    }
    __syncthreads();
    __threadfence();       // acquire: subsequent reads see other blocks' writes
}

// ---------------------------------------------------------------------------
// Persistent decode loop. 256 blocks x 512 threads (cooperative, 1 block/CU).
// Block roles: blk<64 -> step-phase for batch b=blk; all blocks -> GRU for
// j in {2*blk, 2*blk+1}.
__global__ __launch_bounds__(512, 2) void k_loop(
    const float* __restrict__ inputs, const int* __restrict__ tgt,
    const __half* __restrict__ WahT, const float* __restrict__ battn,
    const float* __restrict__ vattn,
    const __half* __restrict__ Wi0h, const __half* __restrict__ Wh0h,
    const float* __restrict__ bi0, const float* __restrict__ bh0,
    const __half* __restrict__ Wi1h, const __half* __restrict__ Wh1h,
    const float* __restrict__ bi1, const float* __restrict__ bh1,
    const __half* __restrict__ Wouth, const float* __restrict__ bout,
    const __half* __restrict__ encph, const float* __restrict__ enc,
    float* __restrict__ h0c, float* __restrict__ h1c, float* __restrict__ h1row,
    float* __restrict__ wsrow, float* __restrict__ wscol, float* __restrict__ curc,
    unsigned int* __restrict__ ctr, float* __restrict__ out)
{
    const int blk = blockIdx.x, t = threadIdx.x;
    const int lane = t & 63, wv = t >> 6;
    const int j0 = blk * 2;

    // ---- LDS: pinned GRU weights for both j's (~24.4 KB) + scratch (~21 KB) ----
    __shared__ __half wi0L[2][3][544];
    __shared__ __half wh0L[2][3][512];
    __shared__ __half wi1L[2][3][512];
    __shared__ __half wh1L[2][3][512];
    __shared__ float h1s[NH], vsL[NH], attsL[NH], battnL[NH];
    __shared__ float2 attp2[2][256];
    __shared__ float pes[NE], outsh[NT];
    __shared__ float invD_sh;
    __shared__ float red[8][64][4];

    // Pin this block's GRU weights in LDS (coalesced, once).
    #pragma unroll
    for (int jl = 0; jl < 2; ++jl) {
        int jj = j0 + jl;
        #pragma unroll
        for (int g3 = 0; g3 < 3; ++g3) {
            for (int c = t; c < 544; c += 512) wi0L[jl][g3][c] = Wi0h[(size_t)(g3*NH + jj)*544 + c];
            wh0L[jl][g3][t] = Wh0h[(size_t)(g3*NH + jj)*NH + t];
            wi1L[jl][g3][t] = Wi1h[(size_t)(g3*NH + jj)*NH + t];
            wh1L[jl][g3][t] = Wh1h[(size_t)(g3*NH + jj)*NH + t];
        }
    }
    // Per-j gate biases into registers (survive fences).
    float bI0[2][3], bH0[2][3], bI1[2][3], bH1[2][3];
    #pragma unroll
    for (int jl = 0; jl < 2; ++jl)
        #pragma unroll
        for (int g3 = 0; g3 < 3; ++g3) {
            int jj = j0 + jl;
            bI0[jl][g3] = bi0[g3*NH + jj]; bH0[jl][g3] = bh0[g3*NH + jj];
            bI1[jl][g3] = bi1[g3*NH + jj]; bH1[jl][g3] = bh1[g3*NH + jj];
        }
    if (blk < NB) { vsL[t] = vattn[t]; battnL[t] = battn[t]; }

    for (int s = 0; s <= NDEC; ++s) {
        const int par = s & 1;
        const float* h0cur = h0c + par*NH*NB;
        float*       h0new = h0c + (par^1)*NH*NB;
        const float* h1cur = h1c + par*NH*NB;
        float*       h1new = h1c + (par^1)*NH*NB;

        // ================= step-phase (blocks 0..63, b = blk) =================
        if (blk < NB) {
            const int b = blk;
            const int do_att = (s < NDEC);
            h1s[t] = h1row[b*NH + t];
            __syncthreads();
            if (s > 0 && wv < NT) {
                const __half* wr = Wouth + (size_t)wv*(2*NH + NF);
                float o = 0.f;
                for (int c = lane; c < 2*NH + NF; c += 64) {
                    float x = (c < NH) ? h1s[c]
                            : (c < 2*NH ? wsrow[b*NH + (c - NH)]
                                        : curc[(c - 2*NH)*NB + b]);
                    o += __half2float(wr[c]) * x;
                }
                #pragma unroll
                for (int off = 32; off; off >>= 1) o += __shfl_down(o, off);
                if (lane == 0) {
                    o += bout[wv];
                    outsh[wv] = o;
                    out[b*(NDEC*NT) + (s-1)*NT + wv] = o;
                }
            }
            __syncthreads();
            if (do_att) {
                if (s > 0) {
                    if (t < NF) curc[t*NB + b] = inputs[b*(NDEC*NF) + (s-1)*NF + t];
                    __syncthreads();
                    if (t < NT) curc[tgt[t]*NB + b] = outsh[t];
                    __syncthreads();
                }
                // att[g] = h1 . Wa_h[g] + battn[g]  (coalesced WahT)
                {
                    int g2 = t & 255, kh = t >> 8;
                    float a0 = 0.f, a1 = 0.f;
                    #pragma unroll 4
                    for (int k = kh*256; k < kh*256 + 256; ++k) {
                        float2 f = __half22float2(*(const __half2*)(WahT + (size_t)k*NH + g2*2));
                        float h = h1s[k];
                        a0 += f.x*h; a1 += f.y*h;
                    }
                    attp2[kh][g2] = make_float2(a0, a1);
                }
                __syncthreads();
                {
                    float2 pa = attp2[0][t>>1], pb = attp2[1][t>>1];
                    attsL[t] = ((t & 1) ? (pa.y + pb.y) : (pa.x + pb.x)) + battnL[t];
                }
                __syncthreads();
                // scores -> exp (no max-subtract: |score| small)
                {
                    float ar[8], vr[8];
                    #pragma unroll
                    for (int i = 0; i < 8; ++i) { ar[i] = attsL[lane*8 + i]; vr[i] = vsL[lane*8 + i]; }
                    for (int it = 0; it < 12; ++it) {
                        int e = wv + it*8;
                        const __half* ep = encph + ((size_t)(b*NE + e))*NH + lane*8;
                        uint4 u = *(const uint4*)ep;
                        __half2 p0 = *(__half2*)&u.x, p1 = *(__half2*)&u.y;
                        __half2 p2 = *(__half2*)&u.z, p3 = *(__half2*)&u.w;
                        float2 f0 = __half22float2(p0), f1 = __half22float2(p1);
                        float2 f2 = __half22float2(p2), f3 = __half22float2(p3);
                        float sacc;
                        sacc  = fast_tanh(f0.x + ar[0]) * vr[0];
                        sacc += fast_tanh(f0.y + ar[1]) * vr[1];
                        sacc += fast_tanh(f1.x + ar[2]) * vr[2];
                        sacc += fast_tanh(f1.y + ar[3]) * vr[3];
                        sacc += fast_tanh(f2.x + ar[4]) * vr[4];
                        sacc += fast_tanh(f2.y + ar[5]) * vr[5];
                        sacc += fast_tanh(f3.x + ar[6]) * vr[6];
                        sacc += fast_tanh(f3.y + ar[7]) * vr[7];
                        #pragma unroll
                        for (int off = 32; off; off >>= 1) sacc += __shfl_down(sacc, off);
                        if (lane == 0) pes[e] = __expf(sacc);
                    }
                }
                __syncthreads();
                if (t < 64) {
                    float v = pes[t] + ((t < 32) ? pes[64 + t] : 0.f);
                    #pragma unroll
                    for (int off = 32; off; off >>= 1) v += __shfl_down(v, off);
                    if (t == 0) invD_sh = 1.f / v;
                }
                __syncthreads();
                // ws[k] = (sum_e p_e * enc[b,e,k]) * invD   (enc fp32, k coalesced)
                {
                    const float* eb = enc + ((size_t)b*NE)*NH + t;
                    float acc = 0.f;
                    #pragma unroll 4
                    for (int e = 0; e < NE; ++e) acc += pes[e] * eb[(size_t)e*NH];
                    float v = acc * invD_sh;
                    wsrow[b*NH + t] = v;
                    wscol[t*NB + b] = v;
                }
            }
        }
        if (s == NDEC) break;

        gbar(ctr + 3*s + 0);   // ws/cur ready

        // ========== GRU layer 0 (all blocks; thread = (b, jl, kq)) ==========
        {
            int b = t & 63, sub = t >> 6, jl = sub & 1, kq = sub >> 1;   // kq in 0..3
            float A0 = 0.f, A1 = 0.f, A2 = 0.f, A3 = 0.f;
            // seg A: cur (K=32, 8/kq)
            #pragma unroll
            for (int k = kq*8; k < kq*8 + 8; k += 2) {
                float x0 = curc[k*NB + b], x1 = curc[(k+1)*NB + b];
                float2 f0 = __half22float2(*(const __half2*)&wi0L[jl][0][k]);
                float2 f1 = __half22float2(*(const __half2*)&wi0L[jl][1][k]);
                float2 f2 = __half22float2(*(const __half2*)&wi0L[jl][2][k]);
                A0 += f0.x*x0 + f0.y*x1; A1 += f1.x*x0 + f1.y*x1; A2 += f2.x*x0 + f2.y*x1;
            }
            // seg B: ws (K=512, 128/kq), Wi cols offset by NF
            #pragma unroll 4
            for (int k = kq*128; k < kq*128 + 128; k += 2) {
                float x0 = wscol[k*NB + b], x1 = wscol[(k+1)*NB + b];
                float2 f0 = __half22float2(*(const __half2*)&wi0L[jl][0][NF + k]);
                float2 f1 = __half22float2(*(const __half2*)&wi0L[jl][1][NF + k]);
                float2 f2 = __half22float2(*(const __half2*)&wi0L[jl][2][NF + k]);
                A0 += f0.x*x0 + f0.y*x1; A1 += f1.x*x0 + f1.y*x1; A2 += f2.x*x0 + f2.y*x1;
            }
            // seg H: h0 recurrent (K=512)
            #pragma unroll 4
            for (int k = kq*128; k < kq*128 + 128; k += 2) {
                float x0 = h0cur[k*NB + b], x1 = h0cur[(k+1)*NB + b];
                float2 f0 = __half22float2(*(const __half2*)&wh0L[jl][0][k]);
                float2 f1 = __half22float2(*(const __half2*)&wh0L[jl][1][k]);
                float2 f2 = __half22float2(*(const __half2*)&wh0L[jl][2][k]);
                A0 += f0.x*x0 + f0.y*x1; A1 += f1.x*x0 + f1.y*x1; A3 += f2.x*x0 + f2.y*x1;
            }
            red[sub][b][0] = A0; red[sub][b][1] = A1; red[sub][b][2] = A2; red[sub][b][3] = A3;
            __syncthreads();
            if (t < 128) {
                int jl2 = t >> 6, bb = t & 63, j = j0 + jl2;
                float S0 = 0.f, S1 = 0.f, S2 = 0.f, S3 = 0.f;
                #pragma unroll
                for (int q = 0; q < 4; ++q) {
                    int sb = q*2 + jl2;
                    S0 += red[sb][bb][0]; S1 += red[sb][bb][1];
                    S2 += red[sb][bb][2]; S3 += red[sb][bb][3];
                }
                float r = fast_sig(S0 + bI0[jl2][0] + bH0[jl2][0]);
                float z = fast_sig(S1 + bI0[jl2][1] + bH0[jl2][1]);
                float n = fast_tanh(S2 + bI0[jl2][2] + r*(S3 + bH0[jl2][2]));
                float hp = h0cur[j*NB + bb];
                h0new[j*NB + bb] = (1.f - z)*n + z*hp;
            }
        }
        gbar(ctr + 3*s + 1);   // h0' ready

        // ================= GRU layer 1 =================
        {
            int b = t & 63, sub = t >> 6, jl = sub & 1, kq = sub >> 1;
            float A0 = 0.f, A1 = 0.f, A2 = 0.f, A3 = 0.f;
            #pragma unroll 4
            for (int k = kq*128; k < kq*128 + 128; k += 2) {
                float x0 = h0new[k*NB + b], x1 = h0new[(k+1)*NB + b];
                float2 f0 = __half22float2(*(const __half2*)&wi1L[jl][0][k]);
                float2 f1 = __half22float2(*(const __half2*)&wi1L[jl][1][k]);
                float2 f2 = __half22float2(*(const __half2*)&wi1L[jl][2][k]);
                A0 += f0.x*x0 + f0.y*x1; A1 += f1.x*x0 + f1.y*x1; A2 += f2.x*x0 + f2.y*x1;
                float h0v = h1cur[k*NB + b], h1v = h1cur[(k+1)*NB + b];
                float2 g0 = __half22float2(*(const __half2*)&wh1L[jl][0][k]);
                float2 g1 = __half22float2(*(const __half2*)&wh1L[jl][1][k]);
                float2 g2 = __half22float2(*(const __half2*)&wh1L[jl][2][k]);
                A0 += g0.x*h0v + g0.y*h1v; A1 += g1.x*h0v + g1.y*h1v; A3 += g2.x*h0v + g2.y*h1v;
            }
            __syncthreads();
            red[sub][b][0] = A0; red[sub][b][1] = A1; red[sub][b][2] = A2; red[sub][b][3] = A3;
            __syncthreads();
            if (t < 128) {
                int jl2 = t >> 6, bb = t & 63, j = j0 + jl2;
                float S0 = 0.f, S1 = 0.f, S2 = 0.f, S3 = 0.f;
                #pragma unroll
                for (int q = 0; q < 4; ++q) {
                    int sb = q*2 + jl2;
                    S0 += red[sb][bb][0]; S1 += red[sb][bb][1];
                    S2 += red[sb][bb][2]; S3 += red[sb][bb][3];
                }
                float r = fast_sig(S0 + bI1[jl2][0] + bH1[jl2][0]);
                float z = fast_sig(S1 + bI1[jl2][1] + bH1[jl2][1]);
                float n = fast_tanh(S2 + bI1[jl2][2] + r*(S3 + bH1[jl2][2]));
                float hp = h1cur[j*NB + bb];
                float hv = (1.f - z)*n + z*hp;
                h1new[j*NB + bb] = hv;
                h1row[bb*NH + j] = hv;
            }
        }
        gbar(ctr + 3*s + 2);   // h1' ready
    }
}

// ---------------------------------------------------------------------------
extern "C" void kernel_launch(void* const* d_in, const int* in_sizes, int n_in,
                              void* d_out, int out_size, void* d_ws, size_t ws_size,
                              hipStream_t stream) {
    const float* inputs = (const float*)d_in[0];
    const float* hidden = (const float*)d_in[1];
    const float* enc    = (const float*)d_in[2];
    const int*   tgt    = (const int*)d_in[3];
    const float* Wattn  = (const float*)d_in[4];
    const float* battn  = (const float*)d_in[5];
    const float* vattn  = (const float*)d_in[6];
    const float* Wi0    = (const float*)d_in[7];
    const float* Wh0    = (const float*)d_in[8];
    const float* bi0    = (const float*)d_in[9];
    const float* bh0    = (const float*)d_in[10];
    const float* Wi1    = (const float*)d_in[11];
    const float* Wh1    = (const float*)d_in[12];
    const float* bi1    = (const float*)d_in[13];
    const float* bh1    = (const float*)d_in[14];
    const float* Wout   = (const float*)d_in[15];
    const float* bout   = (const float*)d_in[16];
    float* out = (float*)d_out;

    // Workspace (≈13.5 MiB)
    float* h0c   = (float*)d_ws;              // 2 x [512][64]
    float* h1c   = h0c + 2*NH*NB;             // 2 x [512][64]
    float* h1row = h1c + 2*NH*NB;             // [64][512]
    float* wsrow = h1row + NB*NH;             // [64][512]
    float* wscol = wsrow + NB*NH;             // [512][64]
    float* curc  = wscol + NH*NB;             // [32][64]
    unsigned int* ctr = (unsigned int*)(curc + NF*NB);   // [64]
    __half* Wi0h  = (__half*)(ctr + 64);      // 1536 x 544
    __half* Wh0h  = Wi0h + 1536*544;          // 1536 x 512
    __half* Wi1h  = Wh0h + 1536*512;
    __half* Wh1h  = Wi1h + 1536*512;
    __half* Wouth = Wh1h + 1536*512;          // 4 x 1056
    __half* WahT  = Wouth + 4*1056;           // [512 k][512 g]
    __half* encph = WahT + 512*512;           // [6144][512]

    k_init<<<NB, 256, 0, stream>>>(hidden, inputs, h0c, h1c, h1row, curc);
    k_prep<<<(1536*544 + 3*1536*512 + 4*1056 + 512*512 + 64 + 255)/256, 256, 0, stream>>>(
        Wi0, Wh0, Wi1, Wh1, Wout, Wattn, Wi0h, Wh0h, Wi1h, Wh1h, Wouth, WahT, ctr);
    k_encproj<<<768, 256, 0, stream>>>(enc, Wattn, encph);

    void* args[] = {
        (void*)&inputs, (void*)&tgt, (void*)&WahT, (void*)&battn, (void*)&vattn,
        (void*)&Wi0h, (void*)&Wh0h, (void*)&bi0, (void*)&bh0,
        (void*)&Wi1h, (void*)&Wh1h, (void*)&bi1, (void*)&bh1,
        (void*)&Wouth, (void*)&bout, (void*)&encph, (void*)&enc,
        (void*)&h0c, (void*)&h1c, (void*)&h1row,
        (void*)&wsrow, (void*)&wscol, (void*)&curc,
        (void*)&ctr, (void*)&out
    };
    hipLaunchCooperativeKernel((void*)k_loop, dim3(NBLK), dim3(512), args, 0, stream);
}

// Round 11
// 964.491 us; speedup vs baseline: 4.4305x; 4.4305x over previous
//
#include <hip/hip_runtime.h>
#include <hip/hip_fp16.h>

// Problem constants
#define NB   64     // batch
#define NDEC 12     // decoder steps
#define NF   32     // input features
#define NH   512    // hidden
#define NE   96     // encoder length
#define NT   4      // output dim

__device__ __forceinline__ float fast_tanh(float x) {
    x = fminf(fmaxf(x, -15.f), 15.f);
    float e = __expf(2.f * x);
    return (e - 1.f) / (e + 1.f);
}
__device__ __forceinline__ float fast_sig(float x) {
    return 1.f / (1.f + __expf(-x));
}

// ---------------------------------------------------------------------------
// One-time: fp32->fp16 weight converts (+ Wa_h transpose) + state init.
__global__ __launch_bounds__(256) void k_prep(
    const float* __restrict__ Wi0, const float* __restrict__ Wh0,
    const float* __restrict__ Wi1, const float* __restrict__ Wh1,
    const float* __restrict__ Wout, const float* __restrict__ Wattn,
    const float* __restrict__ hidden, const float* __restrict__ inputs,
    __half* __restrict__ Wi0h, __half* __restrict__ Wh0h,
    __half* __restrict__ Wi1h, __half* __restrict__ Wh1h,
    __half* __restrict__ Wouth, __half* __restrict__ WahT,
    float* __restrict__ h0c, float* __restrict__ h1c,
    float* __restrict__ h1row, float* __restrict__ curc)
{
    int i = blockIdx.x*256 + threadIdx.x;
    const int n0 = 1536*544, n1 = 1536*512, n4 = 4*1056, n5 = 512*512;
    if (i < n0) { Wi0h[i] = __float2half_rn(Wi0[i]); return; }  i -= n0;
    if (i < n1) { Wh0h[i] = __float2half_rn(Wh0[i]); return; }  i -= n1;
    if (i < n1) { Wi1h[i] = __float2half_rn(Wi1[i]); return; }  i -= n1;
    if (i < n1) { Wh1h[i] = __float2half_rn(Wh1[i]); return; }  i -= n1;
    if (i < n4) { Wouth[i] = __float2half_rn(Wout[i]); return; } i -= n4;
    if (i < n5) {
        int k = i >> 9, g = i & 511;                 // WahT[k][g] = Wattn[g][k]
        WahT[i] = __float2half_rn(Wattn[(size_t)g*1024 + k]);
        return;
    }
    i -= n5;
    if (i < NB*NH) {                                  // state init
        int b = i >> 9, k = i & 511;
        float v0 = hidden[b*NH + k];
        float v1 = hidden[NB*NH + b*NH + k];
        h0c[k*NB + b] = v0;
        h1c[k*NB + b] = v1;
        h1row[b*NH + k] = v1;
        return;
    }
    i -= NB*NH;
    if (i < NB*NF) {                                  // cur(0)
        int b = i >> 5, k = i & 31;
        curc[k*NB + b] = inputs[b*NDEC*NF + k];
    }
}

// ---------------------------------------------------------------------------
// enc_proj[be][g] = sum_h enc[be][h] * W_attn[g][512+h]; stored fp16.
// k-major padded LDS (conflict-free), XCD-aware block swizzle for A-tile reuse.
__global__ __launch_bounds__(256) void k_encproj(const float* __restrict__ enc,
                                                 const float* __restrict__ Wattn,
                                                 __half* __restrict__ encph) {
    __shared__ float As[16][68];   // [k][row]
    __shared__ float Bs[16][68];
    // swizzle: blocks with equal (x%8) (likely same XCD) share few A-tiles
    int x = blockIdx.x;                    // 768 = 96 by * 8 bx
    int bx = (x >> 3) & 7;
    int by = (x & 7) * 12 + (x >> 6);
    int tid = threadIdx.x;
    int tx = tid & 15, ty = tid >> 4;
    int arow = tid >> 2;            // 0..63
    int c4   = tid & 3;             // k-chunk of 4
    const float* Abase = enc   + (size_t)(by*64 + arow)*NH;
    const float* Bbase = Wattn + (size_t)(bx*64 + arow)*(2*NH) + NH;
    float acc[4][4] = {};
    for (int k0 = 0; k0 < NH; k0 += 16) {
        float4 av = *(const float4*)(Abase + k0 + c4*4);
        float4 bv = *(const float4*)(Bbase + k0 + c4*4);
        As[c4*4+0][arow] = av.x; As[c4*4+1][arow] = av.y;
        As[c4*4+2][arow] = av.z; As[c4*4+3][arow] = av.w;
        Bs[c4*4+0][arow] = bv.x; Bs[c4*4+1][arow] = bv.y;
        Bs[c4*4+2][arow] = bv.z; Bs[c4*4+3][arow] = bv.w;
        __syncthreads();
        #pragma unroll
        for (int k = 0; k < 16; ++k) {
            float4 a = *(const float4*)&As[k][ty*4];
            float4 b = *(const float4*)&Bs[k][tx*4];
            acc[0][0] += a.x*b.x; acc[0][1] += a.x*b.y; acc[0][2] += a.x*b.z; acc[0][3] += a.x*b.w;
            acc[1][0] += a.y*b.x; acc[1][1] += a.y*b.y; acc[1][2] += a.y*b.z; acc[1][3] += a.y*b.w;
            acc[2][0] += a.z*b.x; acc[2][1] += a.z*b.y; acc[2][2] += a.z*b.z; acc[2][3] += a.z*b.w;
            acc[3][0] += a.w*b.x; acc[3][1] += a.w*b.y; acc[3][2] += a.w*b.z; acc[3][3] += a.w*b.w;
        }
        __syncthreads();
    }
    #pragma unroll
    for (int i = 0; i < 4; ++i) {
        __half* orow = encph + (size_t)(by*64 + ty*4 + i)*NH + bx*64 + tx*4;
        #pragma unroll
        for (int j = 0; j < 4; j += 2) {
            __half2 h2 = __floats2half2_rn(acc[i][j], acc[i][j+1]);
            *(__half2*)(orow + j) = h2;
        }
    }
}

// ---------------------------------------------------------------------------
// Fused per-step kernel: one block per batch element, 1024 threads.
// out-proj(s-1) + cur(s) + att GEMV (coalesced WahT) + scores + softmax + ws.
__global__ __launch_bounds__(1024) void k_step(
    const float* __restrict__ inputs, const int* __restrict__ tgt,
    const __half* __restrict__ WahT,   // [512 k][512 g]
    const float* __restrict__ battn, const float* __restrict__ vattn,
    const __half* __restrict__ Wouth, const float* __restrict__ bout,
    const __half* __restrict__ encph, const float* __restrict__ enc,
    const float* __restrict__ h1row,   // [64][512] h1(s)
    float* __restrict__ wsrow,         // [64][512]
    float* __restrict__ wscol,         // [512][64]
    float* __restrict__ curc,          // [32][64]
    float* __restrict__ out,
    int s, int do_att)
{
    int b = blockIdx.x, t = threadIdx.x;
    int lane = t & 63, widx = t >> 6;
    __shared__ float h1s[NH], wsp[NH], vs[NH], atts[NH];
    __shared__ float2 attp2[4][256];
    __shared__ float pes[NE], combA[NH], combB[NH], outsh[NT];
    __shared__ float invD_sh;

    if (t < NH) { h1s[t] = h1row[b*NH + t]; vs[t] = vattn[t]; }
    else        { wsp[t - NH] = wsrow[b*NH + (t - NH)]; }
    __syncthreads();

    if (s > 0) {
        if (widx < NT) {
            const __half* wr = Wouth + (size_t)widx*(2*NH + NF);
            float o = 0.f;
            for (int c = lane; c < 2*NH + NF; c += 64) {
                float x = (c < NH) ? h1s[c]
                        : (c < 2*NH ? wsp[c - NH] : curc[(c - 2*NH)*NB + b]);
                o += __half2float(wr[c]) * x;
            }
            #pragma unroll
            for (int off = 32; off; off >>= 1) o += __shfl_down(o, off);
            if (lane == 0) {
                o += bout[widx];
                outsh[widx] = o;
                out[b*(NDEC*NT) + (s-1)*NT + widx] = o;
            }
        }
        __syncthreads();
        if (do_att) {
            if (t < NF) curc[t*NB + b] = inputs[b*(NDEC*NF) + (s-1)*NF + t];
            __syncthreads();
            if (t < NT) curc[tgt[t]*NB + b] = outsh[t];
        }
    }
    if (!do_att) return;

    // att[g] = h1 . Wa_h[g] + battn[g]; coalesced: lane covers g-pairs
    {
        int g2 = t & 255, kq = t >> 8;   // 4 K-quarters of 128
        float a0 = 0.f, a1 = 0.f;
        #pragma unroll 4
        for (int k = kq*128; k < kq*128 + 128; ++k) {
            float2 f = __half22float2(*(const __half2*)(WahT + (size_t)k*NH + g2*2));
            float h = h1s[k];
            a0 += f.x*h; a1 += f.y*h;
        }
        attp2[kq][g2] = make_float2(a0, a1);
    }
    __syncthreads();
    if (t < NH) {
        int g = t;
        float2 p0 = attp2[0][g>>1], p1 = attp2[1][g>>1];
        float2 p2 = attp2[2][g>>1], p3 = attp2[3][g>>1];
        float v = (g & 1) ? (p0.y + p1.y + p2.y + p3.y)
                          : (p0.x + p1.x + p2.x + p3.x);
        atts[g] = v + battn[g];
    }
    __syncthreads();

    // scores -> exp (no max-subtract: |score| small)
    {
        float ar[8], vr[8];
        #pragma unroll
        for (int i = 0; i < 8; ++i) { ar[i] = atts[lane*8 + i]; vr[i] = vs[lane*8 + i]; }
        for (int it = 0; it < 6; ++it) {
            int e = widx + it*16;
            const __half* ep = encph + ((size_t)(b*NE + e))*NH + lane*8;
            uint4 u = *(const uint4*)ep;
            __half2 p0 = *(__half2*)&u.x, p1 = *(__half2*)&u.y;
            __half2 p2 = *(__half2*)&u.z, p3 = *(__half2*)&u.w;
            float2 f0 = __half22float2(p0), f1 = __half22float2(p1);
            float2 f2 = __half22float2(p2), f3 = __half22float2(p3);
            float sacc;
            sacc  = fast_tanh(f0.x + ar[0]) * vr[0];
            sacc += fast_tanh(f0.y + ar[1]) * vr[1];
            sacc += fast_tanh(f1.x + ar[2]) * vr[2];
            sacc += fast_tanh(f1.y + ar[3]) * vr[3];
            sacc += fast_tanh(f2.x + ar[4]) * vr[4];
            sacc += fast_tanh(f2.y + ar[5]) * vr[5];
            sacc += fast_tanh(f3.x + ar[6]) * vr[6];
            sacc += fast_tanh(f3.y + ar[7]) * vr[7];
            #pragma unroll
            for (int off = 32; off; off >>= 1) sacc += __shfl_down(sacc, off);
            if (lane == 0) pes[e] = __expf(sacc);
        }
    }
    __syncthreads();

    if (t < 64) {
        float v = pes[t] + ((t < 32) ? pes[64 + t] : 0.f);
        #pragma unroll
        for (int off = 32; off; off >>= 1) v += __shfl_down(v, off);
        if (t == 0) invD_sh = 1.f / v;
    }
    __syncthreads();

    // ws[k] = sum_e p[e] * enc[b,e,k]  (coalesced over k)
    {
        int k = t & 511, half = t >> 9;
        const float* eb = enc + ((size_t)b*NE + half*48)*NH + k;
        float acc = 0.f;
        #pragma unroll 4
        for (int e = 0; e < 48; ++e) acc += pes[half*48 + e] * eb[(size_t)e*NH];
        if (half == 0) combA[k] = acc; else combB[k] = acc;
    }
    __syncthreads();
    if (t < NH) {
        float v = (combA[t] + combB[t]) * invD_sh;
        wsrow[b*NH + t] = v;
        wscol[t*NB + b] = v;
    }
}

// ---------------------------------------------------------------------------
// GRU: grid 256 (block = j pair), block 512 = (b = t&63, jl = (t>>6)&1,
// kq = t>>7 in [0,4)). Col-major fp32 state (lane-coalesced); fp16 weights
// (wave-uniform broadcast loads).
__global__ __launch_bounds__(512) void k_gru(
    const __half* __restrict__ Wi, const __half* __restrict__ Wh,
    const float* __restrict__ bi, const float* __restrict__ bh,
    const float* __restrict__ xA, int KA,     // [KA][64]
    const float* __restrict__ xB, int KB,     // [512][64] or null
    const float* __restrict__ holdc,          // [512][64]
    float* __restrict__ hnewc,                // [512][64]
    float* __restrict__ hnewrow)              // [64][512] or null
{
    int j0 = blockIdx.x * 2;
    int t = threadIdx.x, b = t & 63, sub = t >> 6, jl = sub & 1, kq = sub >> 1;
    int j = j0 + jl;
    int KIw = KA + KB;
    const __half* w0 = Wi + (size_t)j*KIw;
    const __half* w1 = Wi + (size_t)(NH + j)*KIw;
    const __half* w2 = Wi + (size_t)(2*NH + j)*KIw;
    const __half* v0 = Wh + (size_t)j*NH;
    const __half* v1 = Wh + (size_t)(NH + j)*NH;
    const __half* v2 = Wh + (size_t)(2*NH + j)*NH;
    float A0 = 0.f, A1 = 0.f, A2 = 0.f, A3 = 0.f;

    int lenA = KA >> 2;
    #pragma unroll 4
    for (int k = kq*lenA; k < kq*lenA + lenA; k += 2) {
        float x0 = xA[k*NB + b], x1 = xA[(k+1)*NB + b];
        float2 f0 = __half22float2(*(const __half2*)(w0 + k));
        float2 f1 = __half22float2(*(const __half2*)(w1 + k));
        float2 f2 = __half22float2(*(const __half2*)(w2 + k));
        A0 += f0.x*x0 + f0.y*x1;
        A1 += f1.x*x0 + f1.y*x1;
        A2 += f2.x*x0 + f2.y*x1;
    }
    if (KB > 0) {
        int lenB = KB >> 2;
        #pragma unroll 4
        for (int k = kq*lenB; k < kq*lenB + lenB; k += 2) {
            float x0 = xB[k*NB + b], x1 = xB[(k+1)*NB + b];
            int c = KA + k;
            float2 f0 = __half22float2(*(const __half2*)(w0 + c));
            float2 f1 = __half22float2(*(const __half2*)(w1 + c));
            float2 f2 = __half22float2(*(const __half2*)(w2 + c));
            A0 += f0.x*x0 + f0.y*x1;
            A1 += f1.x*x0 + f1.y*x1;
            A2 += f2.x*x0 + f2.y*x1;
        }
    }
    {
        const int lenH = NH >> 2;   // 128
        #pragma unroll 4
        for (int k = kq*lenH; k < kq*lenH + lenH; k += 2) {
            float x0 = holdc[k*NB + b], x1 = holdc[(k+1)*NB + b];
            float2 f0 = __half22float2(*(const __half2*)(v0 + k));
            float2 f1 = __half22float2(*(const __half2*)(v1 + k));
            float2 f2 = __half22float2(*(const __half2*)(v2 + k));
            A0 += f0.x*x0 + f0.y*x1;
            A1 += f1.x*x0 + f1.y*x1;
            A3 += f2.x*x0 + f2.y*x1;
        }
    }

    __shared__ float red[8][64][4];
    red[sub][b][0] = A0; red[sub][b][1] = A1; red[sub][b][2] = A2; red[sub][b][3] = A3;
    __syncthreads();
    if (t < 128) {
        int jl2 = t >> 6, bb = t & 63, jj = j0 + jl2;
        float S0 = 0.f, S1 = 0.f, S2 = 0.f, S3 = 0.f;
        #pragma unroll
        for (int q = 0; q < 4; ++q) {
            int sb = q*2 + jl2;
            S0 += red[sb][bb][0]; S1 += red[sb][bb][1];
            S2 += red[sb][bb][2]; S3 += red[sb][bb][3];
        }
        float r = fast_sig(S0 + bi[jj] + bh[jj]);
        float z = fast_sig(S1 + bi[NH + jj] + bh[NH + jj]);
        float n = fast_tanh(S2 + bi[2*NH + jj] + r*(S3 + bh[2*NH + jj]));
        float hp = holdc[jj*NB + bb];
        float hv = (1.f - z)*n + z*hp;
        hnewc[jj*NB + bb] = hv;
        if (hnewrow) hnewrow[bb*NH + jj] = hv;
    }
}

// ---------------------------------------------------------------------------
extern "C" void kernel_launch(void* const* d_in, const int* in_sizes, int n_in,
                              void* d_out, int out_size, void* d_ws, size_t ws_size,
                              hipStream_t stream) {
    const float* inputs = (const float*)d_in[0];
    const float* hidden = (const float*)d_in[1];
    const float* enc    = (const float*)d_in[2];
    const int*   tgt    = (const int*)d_in[3];
    const float* Wattn  = (const float*)d_in[4];
    const float* battn  = (const float*)d_in[5];
    const float* vattn  = (const float*)d_in[6];
    const float* Wi0    = (const float*)d_in[7];
    const float* Wh0    = (const float*)d_in[8];
    const float* bi0    = (const float*)d_in[9];
    const float* bh0    = (const float*)d_in[10];
    const float* Wi1    = (const float*)d_in[11];
    const float* Wh1    = (const float*)d_in[12];
    const float* bi1    = (const float*)d_in[13];
    const float* bh1    = (const float*)d_in[14];
    const float* Wout   = (const float*)d_in[15];
    const float* bout   = (const float*)d_in[16];
    float* out = (float*)d_out;

    // Workspace (≈13.5 MiB)
    float* h0c   = (float*)d_ws;              // 2 x [512][64]
    float* h1c   = h0c + 2*NH*NB;             // 2 x [512][64]
    float* h1row = h1c + 2*NH*NB;             // [64][512]
    float* wsrow = h1row + NB*NH;             // [64][512]
    float* wscol = wsrow + NB*NH;             // [512][64]
    float* curc  = wscol + NH*NB;             // [32][64]
    __half* Wi0h  = (__half*)(curc + NF*NB);  // 1536 x 544
    __half* Wh0h  = Wi0h + 1536*544;          // 1536 x 512
    __half* Wi1h  = Wh0h + 1536*512;
    __half* Wh1h  = Wi1h + 1536*512;
    __half* Wouth = Wh1h + 1536*512;          // 4 x 1056
    __half* WahT  = Wouth + 4*1056;           // [512 k][512 g]
    __half* encph = WahT + 512*512;           // [6144][512]

    const int prep_n = 1536*544 + 3*1536*512 + 4*1056 + 512*512 + NB*NH + NB*NF;
    k_prep<<<(prep_n + 255)/256, 256, 0, stream>>>(
        Wi0, Wh0, Wi1, Wh1, Wout, Wattn, hidden, inputs,
        Wi0h, Wh0h, Wi1h, Wh1h, Wouth, WahT, h0c, h1c, h1row, curc);
    k_encproj<<<768, 256, 0, stream>>>(enc, Wattn, encph);

    for (int s = 0; s < NDEC; ++s) {
        int par = s & 1;
        k_step<<<NB, 1024, 0, stream>>>(inputs, tgt, WahT, battn, vattn, Wouth, bout,
                                        encph, enc, h1row, wsrow, wscol, curc, out, s, 1);
        k_gru<<<NH/2, 512, 0, stream>>>(Wi0h, Wh0h, bi0, bh0,
                                        curc, NF, wscol, NH,
                                        h0c + par*NH*NB, h0c + (par^1)*NH*NB, nullptr);
        k_gru<<<NH/2, 512, 0, stream>>>(Wi1h, Wh1h, bi1, bh1,
                                        h0c + (par^1)*NH*NB, NH, nullptr, 0,
                                        h1c + par*NH*NB, h1c + (par^1)*NH*NB, h1row);
    }
    // Final out(11) projection only; h1row holds h1(12)
    k_step<<<NB, 1024, 0, stream>>>(inputs, tgt, WahT, battn, vattn, Wouth, bout,
                                    encph, enc, h1row, wsrow, wscol, curc, out, NDEC, 0);
}

// Round 12
// 765.111 us; speedup vs baseline: 5.5850x; 1.2606x over previous
//
#include <hip/hip_runtime.h>
#include <hip/hip_fp16.h>

// Problem constants
#define NB   64     // batch
#define NDEC 12     // decoder steps
#define NF   32     // input features
#define NH   512    // hidden
#define NE   96     // encoder length
#define NT   4      // output dim

__device__ __forceinline__ float fast_tanh(float x) {
    x = fminf(fmaxf(x, -15.f), 15.f);
    float e = __expf(2.f * x);
    return (e - 1.f) / (e + 1.f);
}
__device__ __forceinline__ float fast_sig(float x) {
    return 1.f / (1.f + __expf(-x));
}

// ---------------------------------------------------------------------------
// One-time: fp32->fp16 weight converts (+ Wa_h transpose) + state init.
__global__ __launch_bounds__(256) void k_prep(
    const float* __restrict__ Wi0, const float* __restrict__ Wh0,
    const float* __restrict__ Wi1, const float* __restrict__ Wh1,
    const float* __restrict__ Wout, const float* __restrict__ Wattn,
    const float* __restrict__ hidden, const float* __restrict__ inputs,
    __half* __restrict__ Wi0h, __half* __restrict__ Wh0h,
    __half* __restrict__ Wi1h, __half* __restrict__ Wh1h,
    __half* __restrict__ Wouth, __half* __restrict__ WahT,
    float* __restrict__ h0c, float* __restrict__ h1c,
    float* __restrict__ h1row, float* __restrict__ curc)
{
    int i = blockIdx.x*256 + threadIdx.x;
    const int n0 = 1536*544, n1 = 1536*512, n4 = 4*1056, n5 = 512*512;
    if (i < n0) { Wi0h[i] = __float2half_rn(Wi0[i]); return; }  i -= n0;
    if (i < n1) { Wh0h[i] = __float2half_rn(Wh0[i]); return; }  i -= n1;
    if (i < n1) { Wi1h[i] = __float2half_rn(Wi1[i]); return; }  i -= n1;
    if (i < n1) { Wh1h[i] = __float2half_rn(Wh1[i]); return; }  i -= n1;
    if (i < n4) { Wouth[i] = __float2half_rn(Wout[i]); return; } i -= n4;
    if (i < n5) {
        int k = i >> 9, g = i & 511;                 // WahT[k][g] = Wattn[g][k]
        WahT[i] = __float2half_rn(Wattn[(size_t)g*1024 + k]);
        return;
    }
    i -= n5;
    if (i < NB*NH) {                                  // state init
        int b = i >> 9, k = i & 511;
        float v0 = hidden[b*NH + k];
        float v1 = hidden[NB*NH + b*NH + k];
        h0c[k*NB + b] = v0;
        h1c[k*NB + b] = v1;
        h1row[b*NH + k] = v1;
        return;
    }
    i -= NB*NH;
    if (i < NB*NF) {                                  // cur(0)
        int b = i >> 5, k = i & 31;
        curc[k*NB + b] = inputs[b*NDEC*NF + k];
    }
}

// ---------------------------------------------------------------------------
// enc_proj[be][g] = sum_h enc[be][h] * W_attn[g][512+h]; stored fp16.
// k-major padded LDS (conflict-free), XCD-aware block swizzle for A-tile reuse.
__global__ __launch_bounds__(256) void k_encproj(const float* __restrict__ enc,
                                                 const float* __restrict__ Wattn,
                                                 __half* __restrict__ encph) {
    __shared__ float As[16][68];   // [k][row]
    __shared__ float Bs[16][68];
    int x = blockIdx.x;                    // 768 = 96 by * 8 bx
    int bx = (x >> 3) & 7;
    int by = (x & 7) * 12 + (x >> 6);
    int tid = threadIdx.x;
    int tx = tid & 15, ty = tid >> 4;
    int arow = tid >> 2;            // 0..63
    int c4   = tid & 3;             // k-chunk of 4
    const float* Abase = enc   + (size_t)(by*64 + arow)*NH;
    const float* Bbase = Wattn + (size_t)(bx*64 + arow)*(2*NH) + NH;
    float acc[4][4] = {};
    for (int k0 = 0; k0 < NH; k0 += 16) {
        float4 av = *(const float4*)(Abase + k0 + c4*4);
        float4 bv = *(const float4*)(Bbase + k0 + c4*4);
        As[c4*4+0][arow] = av.x; As[c4*4+1][arow] = av.y;
        As[c4*4+2][arow] = av.z; As[c4*4+3][arow] = av.w;
        Bs[c4*4+0][arow] = bv.x; Bs[c4*4+1][arow] = bv.y;
        Bs[c4*4+2][arow] = bv.z; Bs[c4*4+3][arow] = bv.w;
        __syncthreads();
        #pragma unroll
        for (int k = 0; k < 16; ++k) {
            float4 a = *(const float4*)&As[k][ty*4];
            float4 b = *(const float4*)&Bs[k][tx*4];
            acc[0][0] += a.x*b.x; acc[0][1] += a.x*b.y; acc[0][2] += a.x*b.z; acc[0][3] += a.x*b.w;
            acc[1][0] += a.y*b.x; acc[1][1] += a.y*b.y; acc[1][2] += a.y*b.z; acc[1][3] += a.y*b.w;
            acc[2][0] += a.z*b.x; acc[2][1] += a.z*b.y; acc[2][2] += a.z*b.z; acc[2][3] += a.z*b.w;
            acc[3][0] += a.w*b.x; acc[3][1] += a.w*b.y; acc[3][2] += a.w*b.z; acc[3][3] += a.w*b.w;
        }
        __syncthreads();
    }
    #pragma unroll
    for (int i = 0; i < 4; ++i) {
        __half* orow = encph + (size_t)(by*64 + ty*4 + i)*NH + bx*64 + tx*4;
        #pragma unroll
        for (int j = 0; j < 4; j += 2) {
            __half2 h2 = __floats2half2_rn(acc[i][j], acc[i][j+1]);
            *(__half2*)(orow + j) = h2;
        }
    }
}

// ---------------------------------------------------------------------------
// Fused per-step kernel, grid = 64 (+96 when do_att):
//  blocks 0..63  : out-proj(s-1) + cur(s) + att GEMV + scores + softmax + ws
//  blocks 64..159: recurrent-half precompute ghb[layer][gate][j][b] =
//                  Wh{0,1}[gate*512+j] . h{0,1}(s)[.,b]  (work-stealing idle CUs)
__global__ __launch_bounds__(1024) void k_step(
    const float* __restrict__ inputs, const int* __restrict__ tgt,
    const __half* __restrict__ WahT,   // [512 k][512 g]
    const float* __restrict__ battn, const float* __restrict__ vattn,
    const __half* __restrict__ Wouth, const float* __restrict__ bout,
    const __half* __restrict__ encph, const float* __restrict__ enc,
    const __half* __restrict__ Wh0h, const __half* __restrict__ Wh1h,
    const float* __restrict__ h0col,   // [512][64] h0(s)
    const float* __restrict__ h1col,   // [512][64] h1(s)
    const float* __restrict__ h1row,   // [64][512] h1(s)
    float* __restrict__ ghb,           // [2][3][512][64]
    float* __restrict__ wsrow,         // [64][512]
    float* __restrict__ wscol,         // [512][64]
    float* __restrict__ curc,          // [32][64]
    float* __restrict__ out,
    int s, int do_att)
{
    int blk = blockIdx.x, t = threadIdx.x;

    if (blk >= NB) {
        // ---------- recurrent-half precompute ----------
        int li = blk - NB;                 // 0..95
        int layer = (li >= 48) ? 1 : 0;
        int idx = layer ? (li - 48) : li;  // 0..47
        int b = t & 63, rsub = t >> 6;     // rsub 0..15
        int row0 = idx*32 + rsub*2;        // 2 rows/thread; 32 rows/block
        const __half* Wh = layer ? Wh1h : Wh0h;
        const float*  st = layer ? h1col : h0col;
        const __half* wrA = Wh + (size_t)(row0    )*NH;
        const __half* wrB = Wh + (size_t)(row0 + 1)*NH;
        float aA = 0.f, aB = 0.f;
        #pragma unroll 8
        for (int k = 0; k < NH; k += 2) {
            float x0 = st[k*NB + b], x1 = st[(k+1)*NB + b];
            float2 fA = __half22float2(*(const __half2*)(wrA + k));
            float2 fB = __half22float2(*(const __half2*)(wrB + k));
            aA += fA.x*x0 + fA.y*x1;
            aB += fB.x*x0 + fB.y*x1;
        }
        float* gdst = ghb + (size_t)layer*3*NH*NB;
        gdst[(size_t)(row0    )*NB + b] = aA;
        gdst[(size_t)(row0 + 1)*NB + b] = aB;
        return;
    }

    int b = blk;
    int lane = t & 63, widx = t >> 6;
    __shared__ float h1s[NH], wsp[NH], vs[NH], atts[NH];
    __shared__ float2 attp2[4][256];
    __shared__ float pes[NE], combA[NH], combB[NH], outsh[NT];
    __shared__ float invD_sh;

    if (t < NH) { h1s[t] = h1row[b*NH + t]; vs[t] = vattn[t]; }
    else        { wsp[t - NH] = wsrow[b*NH + (t - NH)]; }
    __syncthreads();

    if (s > 0) {
        if (widx < NT) {
            const __half* wr = Wouth + (size_t)widx*(2*NH + NF);
            float o = 0.f;
            for (int c = lane; c < 2*NH + NF; c += 64) {
                float x = (c < NH) ? h1s[c]
                        : (c < 2*NH ? wsp[c - NH] : curc[(c - 2*NH)*NB + b]);
                o += __half2float(wr[c]) * x;
            }
            #pragma unroll
            for (int off = 32; off; off >>= 1) o += __shfl_down(o, off);
            if (lane == 0) {
                o += bout[widx];
                outsh[widx] = o;
                out[b*(NDEC*NT) + (s-1)*NT + widx] = o;
            }
        }
        __syncthreads();
        if (do_att) {
            if (t < NF) curc[t*NB + b] = inputs[b*(NDEC*NF) + (s-1)*NF + t];
            __syncthreads();
            if (t < NT) curc[tgt[t]*NB + b] = outsh[t];
        }
    }
    if (!do_att) return;

    // att[g] = h1 . Wa_h[g] + battn[g]; coalesced: lane covers g-pairs
    {
        int g2 = t & 255, kq = t >> 8;   // 4 K-quarters of 128
        float a0 = 0.f, a1 = 0.f;
        #pragma unroll 4
        for (int k = kq*128; k < kq*128 + 128; ++k) {
            float2 f = __half22float2(*(const __half2*)(WahT + (size_t)k*NH + g2*2));
            float h = h1s[k];
            a0 += f.x*h; a1 += f.y*h;
        }
        attp2[kq][g2] = make_float2(a0, a1);
    }
    __syncthreads();
    if (t < NH) {
        int g = t;
        float2 p0 = attp2[0][g>>1], p1 = attp2[1][g>>1];
        float2 p2 = attp2[2][g>>1], p3 = attp2[3][g>>1];
        float v = (g & 1) ? (p0.y + p1.y + p2.y + p3.y)
                          : (p0.x + p1.x + p2.x + p3.x);
        atts[g] = v + battn[g];
    }
    __syncthreads();

    // scores -> exp (no max-subtract: |score| small)
    {
        float ar[8], vr[8];
        #pragma unroll
        for (int i = 0; i < 8; ++i) { ar[i] = atts[lane*8 + i]; vr[i] = vs[lane*8 + i]; }
        for (int it = 0; it < 6; ++it) {
            int e = widx + it*16;
            const __half* ep = encph + ((size_t)(b*NE + e))*NH + lane*8;
            uint4 u = *(const uint4*)ep;
            __half2 p0 = *(__half2*)&u.x, p1 = *(__half2*)&u.y;
            __half2 p2 = *(__half2*)&u.z, p3 = *(__half2*)&u.w;
            float2 f0 = __half22float2(p0), f1 = __half22float2(p1);
            float2 f2 = __half22float2(p2), f3 = __half22float2(p3);
            float sacc;
            sacc  = fast_tanh(f0.x + ar[0]) * vr[0];
            sacc += fast_tanh(f0.y + ar[1]) * vr[1];
            sacc += fast_tanh(f1.x + ar[2]) * vr[2];
            sacc += fast_tanh(f1.y + ar[3]) * vr[3];
            sacc += fast_tanh(f2.x + ar[4]) * vr[4];
            sacc += fast_tanh(f2.y + ar[5]) * vr[5];
            sacc += fast_tanh(f3.x + ar[6]) * vr[6];
            sacc += fast_tanh(f3.y + ar[7]) * vr[7];
            #pragma unroll
            for (int off = 32; off; off >>= 1) sacc += __shfl_down(sacc, off);
            if (lane == 0) pes[e] = __expf(sacc);
        }
    }
    __syncthreads();

    if (t < 64) {
        float v = pes[t] + ((t < 32) ? pes[64 + t] : 0.f);
        #pragma unroll
        for (int off = 32; off; off >>= 1) v += __shfl_down(v, off);
        if (t == 0) invD_sh = 1.f / v;
    }
    __syncthreads();

    // ws[k] = sum_e p[e] * enc[b,e,k]  (coalesced over k)
    {
        int k = t & 511, half = t >> 9;
        const float* eb = enc + ((size_t)b*NE + half*48)*NH + k;
        float acc = 0.f;
        #pragma unroll 4
        for (int e = 0; e < 48; ++e) acc += pes[half*48 + e] * eb[(size_t)e*NH];
        if (half == 0) combA[k] = acc; else combB[k] = acc;
    }
    __syncthreads();
    if (t < NH) {
        float v = (combA[t] + combB[t]) * invD_sh;
        wsrow[b*NH + t] = v;
        wscol[t*NB + b] = v;
    }
}

// ---------------------------------------------------------------------------
// GRU input-half + gate combine: grid 512 (block = one j), block 512 threads
// = (b = t&63, kq = t>>6 in [0,8)). Recurrent half comes precomputed in ghb.
__global__ __launch_bounds__(512) void k_gru(
    const __half* __restrict__ Wi,
    const float* __restrict__ bi, const float* __restrict__ bh,
    const float* __restrict__ xA, int KA,     // [KA][64]
    const float* __restrict__ xB, int KB,     // [512][64] or null
    const float* __restrict__ ghb,            // [3][512][64] Wh . hold
    const float* __restrict__ holdc,          // [512][64]
    float* __restrict__ hnewc,                // [512][64]
    float* __restrict__ hnewrow)              // [64][512] or null
{
    int j = blockIdx.x;
    int t = threadIdx.x, b = t & 63, kq = t >> 6;
    int KIw = KA + KB;
    const __half* w0 = Wi + (size_t)j*KIw;
    const __half* w1 = Wi + (size_t)(NH + j)*KIw;
    const __half* w2 = Wi + (size_t)(2*NH + j)*KIw;
    float A0 = 0.f, A1 = 0.f, A2 = 0.f;

    int lenA = KA >> 3;
    #pragma unroll 4
    for (int k = kq*lenA; k < kq*lenA + lenA; k += 2) {
        float x0 = xA[k*NB + b], x1 = xA[(k+1)*NB + b];
        float2 f0 = __half22float2(*(const __half2*)(w0 + k));
        float2 f1 = __half22float2(*(const __half2*)(w1 + k));
        float2 f2 = __half22float2(*(const __half2*)(w2 + k));
        A0 += f0.x*x0 + f0.y*x1;
        A1 += f1.x*x0 + f1.y*x1;
        A2 += f2.x*x0 + f2.y*x1;
    }
    if (KB > 0) {
        int lenB = KB >> 3;
        #pragma unroll 4
        for (int k = kq*lenB; k < kq*lenB + lenB; k += 2) {
            float x0 = xB[k*NB + b], x1 = xB[(k+1)*NB + b];
            int c = KA + k;
            float2 f0 = __half22float2(*(const __half2*)(w0 + c));
            float2 f1 = __half22float2(*(const __half2*)(w1 + c));
            float2 f2 = __half22float2(*(const __half2*)(w2 + c));
            A0 += f0.x*x0 + f0.y*x1;
            A1 += f1.x*x0 + f1.y*x1;
            A2 += f2.x*x0 + f2.y*x1;
        }
    }

    __shared__ float red[8][64][3];
    red[kq][b][0] = A0; red[kq][b][1] = A1; red[kq][b][2] = A2;
    __syncthreads();
    if (t < 64) {
        float S0 = 0.f, S1 = 0.f, S2 = 0.f;
        #pragma unroll
        for (int q = 0; q < 8; ++q) {
            S0 += red[q][t][0]; S1 += red[q][t][1]; S2 += red[q][t][2];
        }
        float ghr = ghb[(size_t)(0*NH + j)*NB + t];
        float ghz = ghb[(size_t)(1*NH + j)*NB + t];
        float ghn = ghb[(size_t)(2*NH + j)*NB + t];
        float r = fast_sig(S0 + ghr + bi[j] + bh[j]);
        float z = fast_sig(S1 + ghz + bi[NH + j] + bh[NH + j]);
        float n = fast_tanh(S2 + bi[2*NH + j] + r*(ghn + bh[2*NH + j]));
        float hp = holdc[j*NB + t];
        float hv = (1.f - z)*n + z*hp;
        hnewc[j*NB + t] = hv;
        if (hnewrow) hnewrow[t*NH + j] = hv;
    }
}

// ---------------------------------------------------------------------------
extern "C" void kernel_launch(void* const* d_in, const int* in_sizes, int n_in,
                              void* d_out, int out_size, void* d_ws, size_t ws_size,
                              hipStream_t stream) {
    const float* inputs = (const float*)d_in[0];
    const float* hidden = (const float*)d_in[1];
    const float* enc    = (const float*)d_in[2];
    const int*   tgt    = (const int*)d_in[3];
    const float* Wattn  = (const float*)d_in[4];
    const float* battn  = (const float*)d_in[5];
    const float* vattn  = (const float*)d_in[6];
    const float* Wi0    = (const float*)d_in[7];
    const float* Wh0    = (const float*)d_in[8];
    const float* bi0    = (const float*)d_in[9];
    const float* bh0    = (const float*)d_in[10];
    const float* Wi1    = (const float*)d_in[11];
    const float* Wh1    = (const float*)d_in[12];
    const float* bi1    = (const float*)d_in[13];
    const float* bh1    = (const float*)d_in[14];
    const float* Wout   = (const float*)d_in[15];
    const float* bout   = (const float*)d_in[16];
    float* out = (float*)d_out;

    // Workspace (≈14.3 MiB)
    float* h0c   = (float*)d_ws;              // 2 x [512][64]
    float* h1c   = h0c + 2*NH*NB;             // 2 x [512][64]
    float* h1row = h1c + 2*NH*NB;             // [64][512]
    float* wsrow = h1row + NB*NH;             // [64][512]
    float* wscol = wsrow + NB*NH;             // [512][64]
    float* curc  = wscol + NH*NB;             // [32][64]
    float* ghb   = curc + NF*NB;              // [2][3][512][64]
    __half* Wi0h  = (__half*)(ghb + 2*3*NH*NB);  // 1536 x 544
    __half* Wh0h  = Wi0h + 1536*544;          // 1536 x 512
    __half* Wi1h  = Wh0h + 1536*512;
    __half* Wh1h  = Wi1h + 1536*512;
    __half* Wouth = Wh1h + 1536*512;          // 4 x 1056
    __half* WahT  = Wouth + 4*1056;           // [512 k][512 g]
    __half* encph = WahT + 512*512;           // [6144][512]

    const int prep_n = 1536*544 + 3*1536*512 + 4*1056 + 512*512 + NB*NH + NB*NF;
    k_prep<<<(prep_n + 255)/256, 256, 0, stream>>>(
        Wi0, Wh0, Wi1, Wh1, Wout, Wattn, hidden, inputs,
        Wi0h, Wh0h, Wi1h, Wh1h, Wouth, WahT, h0c, h1c, h1row, curc);
    k_encproj<<<768, 256, 0, stream>>>(enc, Wattn, encph);

    for (int s = 0; s < NDEC; ++s) {
        int par = s & 1;
        k_step<<<NB + 96, 1024, 0, stream>>>(
            inputs, tgt, WahT, battn, vattn, Wouth, bout, encph, enc,
            Wh0h, Wh1h, h0c + par*NH*NB, h1c + par*NH*NB, h1row,
            ghb, wsrow, wscol, curc, out, s, 1);
        k_gru<<<NH, 512, 0, stream>>>(Wi0h, bi0, bh0,
                                      curc, NF, wscol, NH,
                                      ghb,
                                      h0c + par*NH*NB, h0c + (par^1)*NH*NB, nullptr);
        k_gru<<<NH, 512, 0, stream>>>(Wi1h, bi1, bh1,
                                      h0c + (par^1)*NH*NB, NH, nullptr, 0,
                                      ghb + 3*NH*NB,
                                      h1c + par*NH*NB, h1c + (par^1)*NH*NB, h1row);
    }
    // Final out(11) projection only; h1row holds h1(12)
    k_step<<<NB, 1024, 0, stream>>>(
        inputs, tgt, WahT, battn, vattn, Wouth, bout, encph, enc,
        Wh0h, Wh1h, h0c, h1c, h1row,
        ghb, wsrow, wscol, curc, out, NDEC, 0);
}

// Round 13
// 764.152 us; speedup vs baseline: 5.5920x; 1.0013x over previous
//
#include <hip/hip_runtime.h>
#include <hip/hip_fp16.h>

// Problem constants
#define NB   64     // batch
#define NDEC 12     // decoder steps
#define NF   32     // input features
#define NH   512    // hidden
#define NE   96     // encoder length
#define NT   4      // output dim

typedef _Float16 half8_t __attribute__((ext_vector_type(8)));
typedef float   float4_t __attribute__((ext_vector_type(4)));

__device__ __forceinline__ float fast_tanh(float x) {
    x = fminf(fmaxf(x, -15.f), 15.f);
    float e = __expf(2.f * x);
    return (e - 1.f) / (e + 1.f);
}
__device__ __forceinline__ float fast_sig(float x) {
    return 1.f / (1.f + __expf(-x));
}

// ---------------------------------------------------------------------------
// One-time: fp32->fp16 weight converts (+ Wa_h transpose, Wa_e fp16) + state init.
__global__ __launch_bounds__(256) void k_prep(
    const float* __restrict__ Wi0, const float* __restrict__ Wh0,
    const float* __restrict__ Wi1, const float* __restrict__ Wh1,
    const float* __restrict__ Wout, const float* __restrict__ Wattn,
    const float* __restrict__ hidden, const float* __restrict__ inputs,
    __half* __restrict__ Wi0h, __half* __restrict__ Wh0h,
    __half* __restrict__ Wi1h, __half* __restrict__ Wh1h,
    __half* __restrict__ Wouth, __half* __restrict__ WahT,
    __half* __restrict__ WaeH,
    float* __restrict__ h0c, float* __restrict__ h1c,
    float* __restrict__ h1row, float* __restrict__ curc)
{
    int i = blockIdx.x*256 + threadIdx.x;
    const int n0 = 1536*544, n1 = 1536*512, n4 = 4*1056, n5 = 512*512;
    if (i < n0) { Wi0h[i] = __float2half_rn(Wi0[i]); return; }  i -= n0;
    if (i < n1) { Wh0h[i] = __float2half_rn(Wh0[i]); return; }  i -= n1;
    if (i < n1) { Wi1h[i] = __float2half_rn(Wi1[i]); return; }  i -= n1;
    if (i < n1) { Wh1h[i] = __float2half_rn(Wh1[i]); return; }  i -= n1;
    if (i < n4) { Wouth[i] = __float2half_rn(Wout[i]); return; } i -= n4;
    if (i < n5) {
        int k = i >> 9, g = i & 511;                 // WahT[k][g] = Wattn[g][k]
        WahT[i] = __float2half_rn(Wattn[(size_t)g*1024 + k]);
        return;
    }
    i -= n5;
    if (i < n5) {                                     // WaeH[g][k] = Wattn[g][512+k]
        int g = i >> 9, k = i & 511;
        WaeH[i] = __float2half_rn(Wattn[(size_t)g*1024 + 512 + k]);
        return;
    }
    i -= n5;
    if (i < NB*NH) {                                  // state init
        int b = i >> 9, k = i & 511;
        float v0 = hidden[b*NH + k];
        float v1 = hidden[NB*NH + b*NH + k];
        h0c[k*NB + b] = v0;
        h1c[k*NB + b] = v1;
        h1row[b*NH + k] = v1;
        return;
    }
    i -= NB*NH;
    if (i < NB*NF) {                                  // cur(0)
        int b = i >> 5, k = i & 31;
        curc[k*NB + b] = inputs[b*NDEC*NF + k];
    }
}

// ---------------------------------------------------------------------------
// enc_proj via MFMA f16: encp[be][g] = sum_k enc[be][k] * WaeH[g][k].
// Block = 64x64 tile (4 waves on m); wave tile 16(m) x 64(n); K=512 in 16 chunks.
// Layouts (gfx950, verified): A[m=lane&15][k=(lane>>4)*8+i], B[k][n=lane&15],
// D[row=(lane>>4)*4+reg][col=lane&15].
__global__ __launch_bounds__(256) void k_encproj(const float* __restrict__ enc,
                                                 const __half* __restrict__ WaeH,
                                                 __half* __restrict__ encph) {
    int x = blockIdx.x;                 // 768 = 96 (m-tiles) x 8 (n-tiles)
    int by = x >> 3, bx = x & 7;
    int t = threadIdx.x, w = t >> 6, lane = t & 63;
    int mr = lane & 15, kq = lane >> 4;          // kq in 0..3
    int m = by*64 + w*16 + mr;
    const float* arow = enc + (size_t)m*NH;
    float4_t acc[4] = {{0.f,0.f,0.f,0.f},{0.f,0.f,0.f,0.f},
                       {0.f,0.f,0.f,0.f},{0.f,0.f,0.f,0.f}};
    for (int kb = 0; kb < NH; kb += 32) {
        int k = kb + kq*8;
        float4 a0 = *(const float4*)(arow + k);
        float4 a1 = *(const float4*)(arow + k + 4);
        half8_t a;
        a[0] = (_Float16)a0.x; a[1] = (_Float16)a0.y;
        a[2] = (_Float16)a0.z; a[3] = (_Float16)a0.w;
        a[4] = (_Float16)a1.x; a[5] = (_Float16)a1.y;
        a[6] = (_Float16)a1.z; a[7] = (_Float16)a1.w;
        #pragma unroll
        for (int j = 0; j < 4; ++j) {
            int n = bx*64 + j*16 + mr;
            half8_t b = *(const half8_t*)(WaeH + (size_t)n*NH + k);
            acc[j] = __builtin_amdgcn_mfma_f32_16x16x32_f16(a, b, acc[j], 0, 0, 0);
        }
    }
    #pragma unroll
    for (int j = 0; j < 4; ++j) {
        int col = bx*64 + j*16 + mr;
        #pragma unroll
        for (int r = 0; r < 4; ++r) {
            int row = by*64 + w*16 + kq*4 + r;
            encph[(size_t)row*NH + col] = __float2half_rn(acc[j][r]);
        }
    }
}

// ---------------------------------------------------------------------------
// Fused per-step kernel, grid = 64 (+96 when do_att):
//  blocks 0..63  : out-proj(s-1) + cur(s) + att GEMV + scores + softmax + ws
//  blocks 64..159: recurrent-half precompute ghb[layer][gate][j][b]
__global__ __launch_bounds__(1024) void k_step(
    const float* __restrict__ inputs, const int* __restrict__ tgt,
    const __half* __restrict__ WahT,   // [512 k][512 g]
    const float* __restrict__ battn, const float* __restrict__ vattn,
    const __half* __restrict__ Wouth, const float* __restrict__ bout,
    const __half* __restrict__ encph, const float* __restrict__ enc,
    const __half* __restrict__ Wh0h, const __half* __restrict__ Wh1h,
    const float* __restrict__ h0col,   // [512][64] h0(s)
    const float* __restrict__ h1col,   // [512][64] h1(s)
    const float* __restrict__ h1row,   // [64][512] h1(s)
    float* __restrict__ ghb,           // [2][3][512][64]
    float* __restrict__ wsrow,         // [64][512]
    float* __restrict__ wscol,         // [512][64]
    float* __restrict__ curc,          // [32][64]
    float* __restrict__ out,
    int s, int do_att)
{
    int blk = blockIdx.x, t = threadIdx.x;

    if (blk >= NB) {
        // ---------- recurrent-half precompute ----------
        int li = blk - NB;                 // 0..95
        int layer = (li >= 48) ? 1 : 0;
        int idx = layer ? (li - 48) : li;  // 0..47
        int b = t & 63, rsub = t >> 6;     // rsub 0..15
        int row0 = idx*32 + rsub*2;        // 2 rows/thread; 32 rows/block
        const __half* Wh = layer ? Wh1h : Wh0h;
        const float*  st = layer ? h1col : h0col;
        const __half* wrA = Wh + (size_t)(row0    )*NH;
        const __half* wrB = Wh + (size_t)(row0 + 1)*NH;
        float aA = 0.f, aB = 0.f;
        #pragma unroll 8
        for (int k = 0; k < NH; k += 2) {
            float x0 = st[k*NB + b], x1 = st[(k+1)*NB + b];
            float2 fA = __half22float2(*(const __half2*)(wrA + k));
            float2 fB = __half22float2(*(const __half2*)(wrB + k));
            aA += fA.x*x0 + fA.y*x1;
            aB += fB.x*x0 + fB.y*x1;
        }
        float* gdst = ghb + (size_t)layer*3*NH*NB;
        gdst[(size_t)(row0    )*NB + b] = aA;
        gdst[(size_t)(row0 + 1)*NB + b] = aB;
        return;
    }

    int b = blk;
    int lane = t & 63, widx = t >> 6;
    __shared__ float h1s[NH], wsp[NH], vs[NH], atts[NH];
    __shared__ float2 attp2[4][256];
    __shared__ float pes[NE], combA[NH], combB[NH], outsh[NT];
    __shared__ float invD_sh;

    if (t < NH) { h1s[t] = h1row[b*NH + t]; vs[t] = vattn[t]; }
    else        { wsp[t - NH] = wsrow[b*NH + (t - NH)]; }
    __syncthreads();

    if (s > 0) {
        if (widx < NT) {
            const __half* wr = Wouth + (size_t)widx*(2*NH + NF);
            float o = 0.f;
            for (int c = lane; c < 2*NH + NF; c += 64) {
                float x = (c < NH) ? h1s[c]
                        : (c < 2*NH ? wsp[c - NH] : curc[(c - 2*NH)*NB + b]);
                o += __half2float(wr[c]) * x;
            }
            #pragma unroll
            for (int off = 32; off; off >>= 1) o += __shfl_down(o, off);
            if (lane == 0) {
                o += bout[widx];
                outsh[widx] = o;
                out[b*(NDEC*NT) + (s-1)*NT + widx] = o;
            }
        }
        __syncthreads();
        if (do_att) {
            if (t < NF) curc[t*NB + b] = inputs[b*(NDEC*NF) + (s-1)*NF + t];
            __syncthreads();
            if (t < NT) curc[tgt[t]*NB + b] = outsh[t];
        }
    }
    if (!do_att) return;

    // att[g] = h1 . Wa_h[g] + battn[g]; coalesced: lane covers g-pairs
    {
        int g2 = t & 255, kq = t >> 8;   // 4 K-quarters of 128
        float a0 = 0.f, a1 = 0.f;
        #pragma unroll 4
        for (int k = kq*128; k < kq*128 + 128; ++k) {
            float2 f = __half22float2(*(const __half2*)(WahT + (size_t)k*NH + g2*2));
            float h = h1s[k];
            a0 += f.x*h; a1 += f.y*h;
        }
        attp2[kq][g2] = make_float2(a0, a1);
    }
    __syncthreads();
    if (t < NH) {
        int g = t;
        float2 p0 = attp2[0][g>>1], p1 = attp2[1][g>>1];
        float2 p2 = attp2[2][g>>1], p3 = attp2[3][g>>1];
        float v = (g & 1) ? (p0.y + p1.y + p2.y + p3.y)
                          : (p0.x + p1.x + p2.x + p3.x);
        atts[g] = v + battn[g];
    }
    __syncthreads();

    // scores -> exp (no max-subtract: |score| small)
    {
        float ar[8], vr[8];
        #pragma unroll
        for (int i = 0; i < 8; ++i) { ar[i] = atts[lane*8 + i]; vr[i] = vs[lane*8 + i]; }
        for (int it = 0; it < 6; ++it) {
            int e = widx + it*16;
            const __half* ep = encph + ((size_t)(b*NE + e))*NH + lane*8;
            uint4 u = *(const uint4*)ep;
            __half2 p0 = *(__half2*)&u.x, p1 = *(__half2*)&u.y;
            __half2 p2 = *(__half2*)&u.z, p3 = *(__half2*)&u.w;
            float2 f0 = __half22float2(p0), f1 = __half22float2(p1);
            float2 f2 = __half22float2(p2), f3 = __half22float2(p3);
            float sacc;
            sacc  = fast_tanh(f0.x + ar[0]) * vr[0];
            sacc += fast_tanh(f0.y + ar[1]) * vr[1];
            sacc += fast_tanh(f1.x + ar[2]) * vr[2];
            sacc += fast_tanh(f1.y + ar[3]) * vr[3];
            sacc += fast_tanh(f2.x + ar[4]) * vr[4];
            sacc += fast_tanh(f2.y + ar[5]) * vr[5];
            sacc += fast_tanh(f3.x + ar[6]) * vr[6];
            sacc += fast_tanh(f3.y + ar[7]) * vr[7];
            #pragma unroll
            for (int off = 32; off; off >>= 1) sacc += __shfl_down(sacc, off);
            if (lane == 0) pes[e] = __expf(sacc);
        }
    }
    __syncthreads();

    if (t < 64) {
        float v = pes[t] + ((t < 32) ? pes[64 + t] : 0.f);
        #pragma unroll
        for (int off = 32; off; off >>= 1) v += __shfl_down(v, off);
        if (t == 0) invD_sh = 1.f / v;
    }
    __syncthreads();

    // ws[k] = sum_e p[e] * enc[b,e,k]  (coalesced over k)
    {
        int k = t & 511, half = t >> 9;
        const float* eb = enc + ((size_t)b*NE + half*48)*NH + k;
        float acc = 0.f;
        #pragma unroll 4
        for (int e = 0; e < 48; ++e) acc += pes[half*48 + e] * eb[(size_t)e*NH];
        if (half == 0) combA[k] = acc; else combB[k] = acc;
    }
    __syncthreads();
    if (t < NH) {
        float v = (combA[t] + combB[t]) * invD_sh;
        wsrow[b*NH + t] = v;
        wscol[t*NB + b] = v;
    }
}

// ---------------------------------------------------------------------------
// GRU input-half + gate combine: grid 512 (block = one j), block 512 threads
// = (b = t&63, kq = t>>6 in [0,8)). Recurrent half comes precomputed in ghb.
__global__ __launch_bounds__(512) void k_gru(
    const __half* __restrict__ Wi,
    const float* __restrict__ bi, const float* __restrict__ bh,
    const float* __restrict__ xA, int KA,     // [KA][64]
    const float* __restrict__ xB, int KB,     // [512][64] or null
    const float* __restrict__ ghb,            // [3][512][64] Wh . hold
    const float* __restrict__ holdc,          // [512][64]
    float* __restrict__ hnewc,                // [512][64]
    float* __restrict__ hnewrow)              // [64][512] or null
{
    int j = blockIdx.x;
    int t = threadIdx.x, b = t & 63, kq = t >> 6;
    int KIw = KA + KB;
    const __half* w0 = Wi + (size_t)j*KIw;
    const __half* w1 = Wi + (size_t)(NH + j)*KIw;
    const __half* w2 = Wi + (size_t)(2*NH + j)*KIw;
    float A0 = 0.f, A1 = 0.f, A2 = 0.f;

    int lenA = KA >> 3;
    #pragma unroll 4
    for (int k = kq*lenA; k < kq*lenA + lenA; k += 2) {
        float x0 = xA[k*NB + b], x1 = xA[(k+1)*NB + b];
        float2 f0 = __half22float2(*(const __half2*)(w0 + k));
        float2 f1 = __half22float2(*(const __half2*)(w1 + k));
        float2 f2 = __half22float2(*(const __half2*)(w2 + k));
        A0 += f0.x*x0 + f0.y*x1;
        A1 += f1.x*x0 + f1.y*x1;
        A2 += f2.x*x0 + f2.y*x1;
    }
    if (KB > 0) {
        int lenB = KB >> 3;
        #pragma unroll 4
        for (int k = kq*lenB; k < kq*lenB + lenB; k += 2) {
            float x0 = xB[k*NB + b], x1 = xB[(k+1)*NB + b];
            int c = KA + k;
            float2 f0 = __half22float2(*(const __half2*)(w0 + c));
            float2 f1 = __half22float2(*(const __half2*)(w1 + c));
            float2 f2 = __half22float2(*(const __half2*)(w2 + c));
            A0 += f0.x*x0 + f0.y*x1;
            A1 += f1.x*x0 + f1.y*x1;
            A2 += f2.x*x0 + f2.y*x1;
        }
    }

    __shared__ float red[8][64][3];
    red[kq][b][0] = A0; red[kq][b][1] = A1; red[kq][b][2] = A2;
    __syncthreads();
    if (t < 64) {
        float S0 = 0.f, S1 = 0.f, S2 = 0.f;
        #pragma unroll
        for (int q = 0; q < 8; ++q) {
            S0 += red[q][t][0]; S1 += red[q][t][1]; S2 += red[q][t][2];
        }
        float ghr = ghb[(size_t)(0*NH + j)*NB + t];
        float ghz = ghb[(size_t)(1*NH + j)*NB + t];
        float ghn = ghb[(size_t)(2*NH + j)*NB + t];
        float r = fast_sig(S0 + ghr + bi[j] + bh[j]);
        float z = fast_sig(S1 + ghz + bi[NH + j] + bh[NH + j]);
        float n = fast_tanh(S2 + bi[2*NH + j] + r*(ghn + bh[2*NH + j]));
        float hp = holdc[j*NB + t];
        float hv = (1.f - z)*n + z*hp;
        hnewc[j*NB + t] = hv;
        if (hnewrow) hnewrow[t*NH + j] = hv;
    }
}

// ---------------------------------------------------------------------------
extern "C" void kernel_launch(void* const* d_in, const int* in_sizes, int n_in,
                              void* d_out, int out_size, void* d_ws, size_t ws_size,
                              hipStream_t stream) {
    const float* inputs = (const float*)d_in[0];
    const float* hidden = (const float*)d_in[1];
    const float* enc    = (const float*)d_in[2];
    const int*   tgt    = (const int*)d_in[3];
    const float* Wattn  = (const float*)d_in[4];
    const float* battn  = (const float*)d_in[5];
    const float* vattn  = (const float*)d_in[6];
    const float* Wi0    = (const float*)d_in[7];
    const float* Wh0    = (const float*)d_in[8];
    const float* bi0    = (const float*)d_in[9];
    const float* bh0    = (const float*)d_in[10];
    const float* Wi1    = (const float*)d_in[11];
    const float* Wh1    = (const float*)d_in[12];
    const float* bi1    = (const float*)d_in[13];
    const float* bh1    = (const float*)d_in[14];
    const float* Wout   = (const float*)d_in[15];
    const float* bout   = (const float*)d_in[16];
    float* out = (float*)d_out;

    // Workspace (≈14.8 MiB)
    float* h0c   = (float*)d_ws;              // 2 x [512][64]
    float* h1c   = h0c + 2*NH*NB;             // 2 x [512][64]
    float* h1row = h1c + 2*NH*NB;             // [64][512]
    float* wsrow = h1row + NB*NH;             // [64][512]
    float* wscol = wsrow + NB*NH;             // [512][64]
    float* curc  = wscol + NH*NB;             // [32][64]
    float* ghb   = curc + NF*NB;              // [2][3][512][64]
    __half* Wi0h  = (__half*)(ghb + 2*3*NH*NB);  // 1536 x 544
    __half* Wh0h  = Wi0h + 1536*544;          // 1536 x 512
    __half* Wi1h  = Wh0h + 1536*512;
    __half* Wh1h  = Wi1h + 1536*512;
    __half* Wouth = Wh1h + 1536*512;          // 4 x 1056
    __half* WahT  = Wouth + 4*1056;           // [512 k][512 g]
    __half* WaeH  = WahT + 512*512;           // [512 g][512 k] fp16
    __half* encph = WaeH + 512*512;           // [6144][512]

    const int prep_n = 1536*544 + 3*1536*512 + 4*1056 + 2*512*512 + NB*NH + NB*NF;
    k_prep<<<(prep_n + 255)/256, 256, 0, stream>>>(
        Wi0, Wh0, Wi1, Wh1, Wout, Wattn, hidden, inputs,
        Wi0h, Wh0h, Wi1h, Wh1h, Wouth, WahT, WaeH, h0c, h1c, h1row, curc);
    k_encproj<<<768, 256, 0, stream>>>(enc, WaeH, encph);

    for (int s = 0; s < NDEC; ++s) {
        int par = s & 1;
        k_step<<<NB + 96, 1024, 0, stream>>>(
            inputs, tgt, WahT, battn, vattn, Wouth, bout, encph, enc,
            Wh0h, Wh1h, h0c + par*NH*NB, h1c + par*NH*NB, h1row,
            ghb, wsrow, wscol, curc, out, s, 1);
        k_gru<<<NH, 512, 0, stream>>>(Wi0h, bi0, bh0,
                                      curc, NF, wscol, NH,
                                      ghb,
                                      h0c + par*NH*NB, h0c + (par^1)*NH*NB, nullptr);
        k_gru<<<NH, 512, 0, stream>>>(Wi1h, bi1, bh1,
                                      h0c + (par^1)*NH*NB, NH, nullptr, 0,
                                      ghb + 3*NH*NB,
                                      h1c + par*NH*NB, h1c + (par^1)*NH*NB, h1row);
    }
    // Final out(11) projection only; h1row holds h1(12)
    k_step<<<NB, 1024, 0, stream>>>(
        inputs, tgt, WahT, battn, vattn, Wouth, bout, encph, enc,
        Wh0h, Wh1h, h0c, h1c, h1row,
        ghb, wsrow, wscol, curc, out, NDEC, 0);
}